// Round 2
// baseline (336.608 us; speedup 1.0000x reference)
//
#include <hip/hip_runtime.h>
#include <stdint.h>

// Problem constants
#define B_  16
#define C_  256
#define T_  2048
#define K_  1024
#define TOTAL_ELEMS 8388608   // B*C*T

// ---------- packed (dist, idx) ordering helpers ----------
__device__ __forceinline__ unsigned long long pack_key(float d, int idx) {
  unsigned u = __float_as_uint(d);
  u = (u & 0x80000000u) ? ~u : (u | 0x80000000u);   // monotone map f32 -> u32
  return ((unsigned long long)u << 32) | (unsigned)idx;
}
__device__ __forceinline__ float unpack_dist(unsigned long long key) {
  unsigned du = (unsigned)(key >> 32);
  unsigned bits = (du & 0x80000000u) ? (du ^ 0x80000000u) : ~du;
  return __uint_as_float(bits);
}

// ---------- row norms of the three codebooks: nrm[3*1024] ----------
__global__ __launch_bounds__(256) void norms_kernel(
    const float* __restrict__ e0, const float* __restrict__ e1,
    const float* __restrict__ e2, float* __restrict__ nrm) {
  int i = blockIdx.x * 256 + threadIdx.x;     // 0..3071
  const float* e = (i < 1024) ? e0 : (i < 2048) ? e1 : e2;
  const float* p = e + (size_t)(i & 1023) * C_;
  float s = 0.0f;
  for (int c = 0; c < C_; c += 4) {
    float4 v = *(const float4*)(p + c);
    s = fmaf(v.x, v.x, s); s = fmaf(v.y, v.y, s);
    s = fmaf(v.z, v.z, s); s = fmaf(v.w, v.w, s);
  }
  nrm[i] = s;
}

// ---------- code-to-code nearest map: map[k]=argmin_j ||A[k]-B[j]||^2 ----------
// grid = 256 blocks, 4 A-rows per block; each thread owns 4 B-rows.
__global__ __launch_bounds__(256) void map_kernel(
    const float* __restrict__ eA, const float* __restrict__ eB,
    const float* __restrict__ nA, const float* __restrict__ nB,
    int* __restrict__ map, float* __restrict__ dmin) {
  __shared__ float As[4][C_];
  __shared__ unsigned long long kl[4][4];
  int tid = threadIdx.x;
  int kt = blockIdx.x * 4;
  {
    int row = tid >> 6;              // 0..3
    int c0 = (tid & 63) * 4;         // 0..252
    *(float4*)&As[row][c0] = *(const float4*)(eA + (size_t)(kt + row) * C_ + c0);
  }
  __syncthreads();

  int j0 = tid * 4;
  float acc[4][4];   // [B-row q][A-row k]
#pragma unroll
  for (int q = 0; q < 4; q++)
#pragma unroll
    for (int k = 0; k < 4; k++) acc[q][k] = 0.0f;

  for (int cc = 0; cc < C_; cc += 4) {
    float4 bq[4];
#pragma unroll
    for (int q = 0; q < 4; q++)
      bq[q] = *(const float4*)(eB + (size_t)(j0 + q) * C_ + cc);
#pragma unroll
    for (int k = 0; k < 4; k++) {
      float4 a = *(const float4*)&As[k][cc];
#pragma unroll
      for (int q = 0; q < 4; q++) {
        acc[q][k] = fmaf(a.x, bq[q].x, acc[q][k]);
        acc[q][k] = fmaf(a.y, bq[q].y, acc[q][k]);
        acc[q][k] = fmaf(a.z, bq[q].z, acc[q][k]);
        acc[q][k] = fmaf(a.w, bq[q].w, acc[q][k]);
      }
    }
  }

  int lane = tid & 63, wv = tid >> 6;
#pragma unroll
  for (int k = 0; k < 4; k++) {
    unsigned long long best = 0xFFFFFFFFFFFFFFFFULL;
#pragma unroll
    for (int q = 0; q < 4; q++) {
      float s = nB[j0 + q] - 2.0f * acc[q][k];
      unsigned long long key = pack_key(s, j0 + q);
      if (key < best) best = key;
    }
    for (int off = 32; off > 0; off >>= 1) {
      unsigned long long o = __shfl_down(best, off, 64);
      if (o < best) best = o;
    }
    if (lane == 0) kl[k][wv] = best;
  }
  __syncthreads();
  if (tid < 4) {
    unsigned long long best = kl[tid][0];
#pragma unroll
    for (int w = 1; w < 4; w++) if (kl[tid][w] < best) best = kl[tid][w];
    map[kt + tid]  = (int)(best & 0xFFFFFFFFULL);
    dmin[kt + tid] = nA[kt + tid] + unpack_dist(best);
  }
}

// ---------- layer-0 distance GEMM + argmin ----------
// C-tile: 128 rows (t) x 128 codes, block 256 threads, 8x8 micro-tile.
// s_k = ||e_k||^2 - 2 * dot(f, e_k)   (row-constant ||f||^2 dropped)
__global__ __launch_bounds__(256) void l0_kernel(
    const float* __restrict__ x, const float* __restrict__ emb,
    const float* __restrict__ e0n, unsigned long long* __restrict__ keys) {
  __shared__ float As[8][128];   // As[c][t_local]
  __shared__ float Bs[8][128];   // Bs[c][k_local]
  __shared__ unsigned long long kred[128][16];

  int tid = threadIdx.x;
  int mb = blockIdx.x & 255;     // 256 row tiles
  int nb = blockIdx.x >> 8;      // 8 col tiles
  int b  = mb >> 4;              // 16 row-tiles per batch (2048/128)
  int t0 = (mb & 15) << 7;
  const float* xb = x + ((size_t)b << 19);   // b*C*T
  int k0 = nb << 7;

  int tx = tid & 15, ty = tid >> 4;
  int a_c = tid >> 5;            // 0..7
  int a_t = (tid & 31) << 2;     // 0..124
  int b_k = tid >> 1;            // 0..127
  int b_c = (tid & 1) << 2;      // 0 or 4

  float acc[8][8];
#pragma unroll
  for (int i = 0; i < 8; i++)
#pragma unroll
    for (int j = 0; j < 8; j++) acc[i][j] = 0.0f;

  const float* aptr = xb + (size_t)a_c * T_ + t0 + a_t;
  const float* bptr = emb + (size_t)(k0 + b_k) * C_ + b_c;

  for (int cc = 0; cc < C_; cc += 8) {
    float4 av = *(const float4*)(aptr + (size_t)cc * T_);
    float4 bv = *(const float4*)(bptr + cc);
    __syncthreads();
    *(float4*)&As[a_c][a_t] = av;
    Bs[b_c + 0][b_k] = bv.x;
    Bs[b_c + 1][b_k] = bv.y;
    Bs[b_c + 2][b_k] = bv.z;
    Bs[b_c + 3][b_k] = bv.w;
    __syncthreads();
#pragma unroll
    for (int c = 0; c < 8; c++) {
      // As: 4 distinct 32B reads per wave (16-lane broadcast groups) - conflict-free
      float4 a0 = *(const float4*)&As[c][ty * 8];
      float4 a1 = *(const float4*)&As[c][ty * 8 + 4];
      // Bs: split at tx*4 / 64+tx*4 -> 2-way bank aliasing only (free, m136)
      float4 b0 = *(const float4*)&Bs[c][tx * 4];
      float4 b1 = *(const float4*)&Bs[c][64 + tx * 4];
      float av_[8] = {a0.x, a0.y, a0.z, a0.w, a1.x, a1.y, a1.z, a1.w};
      float bv_[8] = {b0.x, b0.y, b0.z, b0.w, b1.x, b1.y, b1.z, b1.w};
#pragma unroll
      for (int i = 0; i < 8; i++)
#pragma unroll
        for (int j = 0; j < 8; j++)
          acc[i][j] = fmaf(av_[i], bv_[j], acc[i][j]);
    }
  }

  // per-thread best over its 8 codes, per row
  int kb0 = k0 + tx * 4;         // codes for j=0..3
  int kb1 = k0 + 64 + tx * 4;    // codes for j=4..7
#pragma unroll
  for (int i = 0; i < 8; i++) {
    unsigned long long best = 0xFFFFFFFFFFFFFFFFULL;
#pragma unroll
    for (int j = 0; j < 8; j++) {
      int k = (j < 4 ? kb0 + j : kb1 + (j - 4));
      float s = e0n[k] - 2.0f * acc[i][j];
      unsigned long long key = pack_key(s, k);
      if (key < best) best = key;
    }
    kred[ty * 8 + i][tx] = best;
  }
  __syncthreads();
  if (tid < 128) {
    unsigned long long best = kred[tid][0];
#pragma unroll
    for (int j = 1; j < 16; j++) if (kred[tid][j] < best) best = kred[tid][j];
    atomicMin(&keys[(size_t)mb * 128 + tid], best);
  }
}

// ---------- gather output + loss ----------
// grid: B * (T/64) = 512 blocks; 256 threads: tt = tid&63 (t), w = tid>>6 (c-quarter)
__global__ __launch_bounds__(256) void finish_kernel(
    const float* __restrict__ x, const float* __restrict__ emb2,
    const unsigned long long* __restrict__ keys,
    const int* __restrict__ map1, const float* __restrict__ d1,
    const int* __restrict__ map2, const float* __restrict__ d2,
    float* __restrict__ out, float* __restrict__ loss_accum) {
  __shared__ int code2_l[64];
  __shared__ float rloss[64];
  __shared__ float fpart[4][64];
  int tid = threadIdx.x;
  int b  = blockIdx.x >> 5;
  int t0 = (blockIdx.x & 31) << 6;
  int tt = tid & 63, w = tid >> 6;

  if (w == 0) {
    unsigned long long key = keys[(size_t)b * T_ + t0 + tt];
    int idx0 = (int)(key & 0xFFFFFFFFULL);
    float smin = unpack_dist(key);
    int c1 = map1[idx0];
    code2_l[tt] = map2[c1];
    rloss[tt] = smin + d1[idx0] + d2[c1];
  }
  __syncthreads();

  const float* xb = x + ((size_t)b << 19);
  float* ob = out + ((size_t)b << 19);
  int code2 = code2_l[tt];
  const float* e2row = emb2 + (size_t)code2 * C_;
  float fn = 0.0f;
  for (int c4 = w * 64; c4 < w * 64 + 64; c4 += 4) {
    float4 ev = *(const float4*)(e2row + c4);
    float evv[4] = {ev.x, ev.y, ev.z, ev.w};
#pragma unroll
    for (int u = 0; u < 4; u++) {
      size_t off = (size_t)(c4 + u) * T_ + t0 + tt;
      float v = xb[off];
      fn = fmaf(v, v, fn);
      ob[off] = evv[u];
    }
  }
  fpart[w][tt] = fn;
  __syncthreads();
  if (w == 0) {
    float tot = fpart[0][tt] + fpart[1][tt] + fpart[2][tt] + fpart[3][tt] + rloss[tt];
    for (int off = 32; off > 0; off >>= 1)
      tot += __shfl_down(tot, off, 64);
    if (tt == 0) atomicAdd(loss_accum, tot);
  }
}

__global__ void finalize_kernel(const float* __restrict__ loss_accum,
                                float* __restrict__ out_loss) {
  *out_loss = 2.0f * (*loss_accum) / 8388608.0f;
}

extern "C" void kernel_launch(void* const* d_in, const int* in_sizes, int n_in,
                              void* d_out, int out_size, void* d_ws, size_t ws_size,
                              hipStream_t stream) {
  const float* x  = (const float*)d_in[0];
  const float* e0 = (const float*)d_in[1];
  const float* e1 = (const float*)d_in[2];
  const float* e2 = (const float*)d_in[3];
  float* out = (float*)d_out;
  char* ws = (char*)d_ws;

  unsigned long long* keys = (unsigned long long*)ws;        // 32768*8 = 262144 B
  float* nrm  = (float*)(ws + 262144);                       // 3*1024*4 = 12288 B
  int*   map1 = (int*)(ws + 274432);                         // 4096 B
  float* d1   = (float*)(ws + 278528);                       // 4096 B
  int*   map2 = (int*)(ws + 282624);                         // 4096 B
  float* d2   = (float*)(ws + 286720);                       // 4096 B
  float* loss_accum = (float*)(ws + 290816);                 // 4 B

  hipMemsetAsync(keys, 0xFF, 262144, stream);
  hipMemsetAsync(loss_accum, 0, 4, stream);

  norms_kernel<<<12, 256, 0, stream>>>(e0, e1, e2, nrm);
  map_kernel<<<256, 256, 0, stream>>>(e0, e1, nrm, nrm + 1024, map1, d1);
  map_kernel<<<256, 256, 0, stream>>>(e1, e2, nrm + 1024, nrm + 2048, map2, d2);
  l0_kernel<<<2048, 256, 0, stream>>>(x, e0, nrm, keys);
  finish_kernel<<<512, 256, 0, stream>>>(x, e2, keys, map1, d1, map2, d2, out, loss_accum);
  finalize_kernel<<<1, 1, 0, stream>>>(loss_accum, out + TOTAL_ELEMS);
}

// Round 3
// 183.636 us; speedup vs baseline: 1.8330x; 1.8330x over previous
//
#include <hip/hip_runtime.h>
#include <stdint.h>

// Problem constants
#define B_  16
#define C_  256
#define T_  2048
#define K_  1024
#define TOTAL_ELEMS 8388608   // B*C*T

typedef short bf16x8 __attribute__((ext_vector_type(8)));
typedef float f32x4 __attribute__((ext_vector_type(4)));

// ---------- packed (dist, idx) ordering helpers ----------
__device__ __forceinline__ unsigned long long pack_key(float d, int idx) {
  unsigned u = __float_as_uint(d);
  u = (u & 0x80000000u) ? ~u : (u | 0x80000000u);   // monotone map f32 -> u32
  return ((unsigned long long)u << 32) | (unsigned)idx;
}
__device__ __forceinline__ float unpack_dist(unsigned long long key) {
  unsigned du = (unsigned)(key >> 32);
  unsigned bits = (du & 0x80000000u) ? (du ^ 0x80000000u) : ~du;
  return __uint_as_float(bits);
}

__device__ __forceinline__ unsigned short f2bf_rne(float f) {
  unsigned u = __float_as_uint(f);
  unsigned r = u + 0x7FFFu + ((u >> 16) & 1u);
  return (unsigned short)(r >> 16);
}

__device__ __forceinline__ void gload_lds16(const void* g, void* l) {
  __builtin_amdgcn_global_load_lds(
      (const __attribute__((address_space(1))) unsigned int*)g,
      (__attribute__((address_space(3))) unsigned int*)l, 16, 0, 0);
}

// ---------- row norms of the three codebooks: nrm[3*1024] ----------
__global__ __launch_bounds__(256) void norms_kernel(
    const float* __restrict__ e0, const float* __restrict__ e1,
    const float* __restrict__ e2, float* __restrict__ nrm) {
  int i = blockIdx.x * 256 + threadIdx.x;     // 0..3071
  const float* e = (i < 1024) ? e0 : (i < 2048) ? e1 : e2;
  const float* p = e + (size_t)(i & 1023) * C_;
  float s = 0.0f;
  for (int c = 0; c < C_; c += 4) {
    float4 v = *(const float4*)(p + c);
    s = fmaf(v.x, v.x, s); s = fmaf(v.y, v.y, s);
    s = fmaf(v.z, v.z, s); s = fmaf(v.w, v.w, s);
  }
  nrm[i] = s;
}

// ---------- convert e0 -> bf16 (linear, coalesced) ----------
__global__ __launch_bounds__(256) void cvt_e0_kernel(
    const float* __restrict__ e0, unsigned short* __restrict__ ebf) {
  int i = blockIdx.x * 256 + threadIdx.x;     // quad id, 0..65535
  float4 v = *(const float4*)(e0 + (size_t)i * 4);
  unsigned lo = (unsigned)f2bf_rne(v.x) | ((unsigned)f2bf_rne(v.y) << 16);
  unsigned hi = (unsigned)f2bf_rne(v.z) | ((unsigned)f2bf_rne(v.w) << 16);
  *(uint2*)(ebf + (size_t)i * 4) = make_uint2(lo, hi);
}

// ---------- transpose+convert x[b][c][t] f32 -> xT[b*T+t][c] bf16 ----------
// grid = 16 * 32 * 4 = 2048 blocks, 64x64 tile each
__global__ __launch_bounds__(256) void xpose_kernel(
    const float* __restrict__ x, unsigned short* __restrict__ xT) {
  __shared__ float ftile[64][68];   // +4 pad: float4-aligned rows, spread banks
  int tid = threadIdx.x;
  int bid = blockIdx.x;
  int b  = bid >> 7;
  int t0 = ((bid >> 2) & 31) << 6;
  int c0 = (bid & 3) << 6;
  int w = tid >> 6, l = tid & 63;
  int c_loc = w * 16 + (l >> 4);
  int t_loc = (l & 15) * 4;
  const float* src = x + (size_t)b * (C_ * T_) + (size_t)(c0 + c_loc) * T_ + t0 + t_loc;
  float4 v = *(const float4*)src;
  *(float4*)&ftile[c_loc][t_loc] = v;
  __syncthreads();
  int t_row = tid >> 2;
  int cs = (tid & 3) * 16;
  unsigned pk[8];
#pragma unroll
  for (int i = 0; i < 8; i++) {
    unsigned short lo = f2bf_rne(ftile[cs + 2 * i][t_row]);
    unsigned short hi = f2bf_rne(ftile[cs + 2 * i + 1][t_row]);
    pk[i] = (unsigned)lo | ((unsigned)hi << 16);
  }
  unsigned short* dst = xT + ((size_t)(b * T_ + t0 + t_row) * C_ + c0 + cs);
  *(uint4*)dst       = make_uint4(pk[0], pk[1], pk[2], pk[3]);
  *((uint4*)dst + 1) = make_uint4(pk[4], pk[5], pk[6], pk[7]);
}

// ---------- code-to-code nearest map (f32, precision-critical) ----------
__global__ __launch_bounds__(256) void map_kernel(
    const float* __restrict__ eA, const float* __restrict__ eB,
    const float* __restrict__ nA, const float* __restrict__ nB,
    int* __restrict__ map, float* __restrict__ dmin) {
  __shared__ float As[4][C_];
  __shared__ unsigned long long kl[4][4];
  int tid = threadIdx.x;
  int kt = blockIdx.x * 4;
  {
    int row = tid >> 6;
    int c0 = (tid & 63) * 4;
    *(float4*)&As[row][c0] = *(const float4*)(eA + (size_t)(kt + row) * C_ + c0);
  }
  __syncthreads();

  int j0 = tid * 4;
  float acc[4][4];
#pragma unroll
  for (int q = 0; q < 4; q++)
#pragma unroll
    for (int k = 0; k < 4; k++) acc[q][k] = 0.0f;

  for (int cc = 0; cc < C_; cc += 4) {
    float4 bq[4];
#pragma unroll
    for (int q = 0; q < 4; q++)
      bq[q] = *(const float4*)(eB + (size_t)(j0 + q) * C_ + cc);
#pragma unroll
    for (int k = 0; k < 4; k++) {
      float4 a = *(const float4*)&As[k][cc];
#pragma unroll
      for (int q = 0; q < 4; q++) {
        acc[q][k] = fmaf(a.x, bq[q].x, acc[q][k]);
        acc[q][k] = fmaf(a.y, bq[q].y, acc[q][k]);
        acc[q][k] = fmaf(a.z, bq[q].z, acc[q][k]);
        acc[q][k] = fmaf(a.w, bq[q].w, acc[q][k]);
      }
    }
  }

  int lane = tid & 63, wv = tid >> 6;
#pragma unroll
  for (int k = 0; k < 4; k++) {
    unsigned long long best = 0xFFFFFFFFFFFFFFFFULL;
#pragma unroll
    for (int q = 0; q < 4; q++) {
      float s = nB[j0 + q] - 2.0f * acc[q][k];
      unsigned long long key = pack_key(s, j0 + q);
      if (key < best) best = key;
    }
    for (int off = 32; off > 0; off >>= 1) {
      unsigned long long o = __shfl_down(best, off, 64);
      if (o < best) best = o;
    }
    if (lane == 0) kl[k][wv] = best;
  }
  __syncthreads();
  if (tid < 4) {
    unsigned long long best = kl[tid][0];
#pragma unroll
    for (int w = 1; w < 4; w++) if (kl[tid][w] < best) best = kl[tid][w];
    map[kt + tid]  = (int)(best & 0xFFFFFFFFULL);
    dmin[kt + tid] = nA[kt + tid] + unpack_dist(best);
  }
}

// ---------- layer-0 MFMA distance GEMM + argmin ----------
// 128x128 tile, BK=32, 4 waves (2x2), per-wave 64x64 via 4x4 16x16x32 frags.
// Source-side XOR k-slot swizzle (slot s of row m holds k-group s^(m&3)).
__global__ __launch_bounds__(256) void l0_mfma_kernel(
    const unsigned short* __restrict__ xT, const unsigned short* __restrict__ ebf,
    const float* __restrict__ e0n, unsigned long long* __restrict__ keys) {
  __shared__ __align__(16) unsigned short AB[2][2][128][32];  // [buf][A/B][row][k]
  __shared__ unsigned long long kred[128][2];

  int tid = threadIdx.x;
  int l = tid & 63, w = tid >> 6;
  int wr = w >> 1, wc = w & 1;
  int mb = blockIdx.x & 255, nb = blockIdx.x >> 8;
  int row0 = mb << 7, kb = nb << 7;

  // staging: wave w stages rows [w*32, w*32+32) of both tiles (2 rounds of 16)
  int sm = w * 32 + (l >> 2);
  int ks = (l & 3) ^ ((l >> 2) & 3);   // source k-seg for dest slot (l&3)
  const unsigned short* gA = xT + ((size_t)(row0 + sm) * C_ + ks * 8);
  const unsigned short* gB = ebf + ((size_t)(kb + sm) * C_ + ks * 8);

  f32x4 acc[4][4];
#pragma unroll
  for (int mi = 0; mi < 4; mi++)
#pragma unroll
    for (int ni = 0; ni < 4; ni++) acc[mi][ni] = (f32x4){0.f, 0.f, 0.f, 0.f};

#define STAGE(buf, kk) do {                                              \
    char* baseA = (char*)&AB[(buf)][0][0][0] + w * 2048;                 \
    char* baseB = (char*)&AB[(buf)][1][0][0] + w * 2048;                 \
    gload_lds16(gA + (size_t)(kk) * 32, baseA);                          \
    gload_lds16(gA + (size_t)16 * C_ + (size_t)(kk) * 32, baseA + 1024); \
    gload_lds16(gB + (size_t)(kk) * 32, baseB);                          \
    gload_lds16(gB + (size_t)16 * C_ + (size_t)(kk) * 32, baseB + 1024); \
  } while (0)

  STAGE(0, 0);
  __syncthreads();

  int lr = l & 15, lg = l >> 4;
  int slot = lg ^ (lr & 3);            // read-side swizzle (same involution)
  int buf = 0;
  for (int kk = 0; kk < 8; kk++) {
    if (kk < 7) STAGE(buf ^ 1, kk + 1);
    bf16x8 aF[4], bF[4];
#pragma unroll
    for (int mi = 0; mi < 4; mi++)
      aF[mi] = *(const bf16x8*)&AB[buf][0][wr * 64 + mi * 16 + lr][slot * 8];
#pragma unroll
    for (int ni = 0; ni < 4; ni++)
      bF[ni] = *(const bf16x8*)&AB[buf][1][wc * 64 + ni * 16 + lr][slot * 8];
#pragma unroll
    for (int mi = 0; mi < 4; mi++)
#pragma unroll
      for (int ni = 0; ni < 4; ni++)
        acc[mi][ni] = __builtin_amdgcn_mfma_f32_16x16x32_bf16(
            aF[mi], bF[ni], acc[mi][ni], 0, 0, 0);
    __syncthreads();
    buf ^= 1;
  }
#undef STAGE

  // epilogue: per-row argmin over this block's 128 codes
  float nv[4];
#pragma unroll
  for (int ni = 0; ni < 4; ni++) nv[ni] = e0n[kb + wc * 64 + ni * 16 + lr];

#pragma unroll
  for (int mi = 0; mi < 4; mi++) {
#pragma unroll
    for (int r = 0; r < 4; r++) {
      unsigned long long best = 0xFFFFFFFFFFFFFFFFULL;
#pragma unroll
      for (int ni = 0; ni < 4; ni++) {
        int code = kb + wc * 64 + ni * 16 + lr;
        float s = nv[ni] - 2.0f * acc[mi][ni][r];
        unsigned long long key = pack_key(s, code);
        if (key < best) best = key;
      }
#pragma unroll
      for (int off = 1; off < 16; off <<= 1) {
        unsigned long long o = __shfl_xor(best, off, 64);
        if (o < best) best = o;
      }
      if (lr == 0) kred[wr * 64 + mi * 16 + lg * 4 + r][wc] = best;
    }
  }
  __syncthreads();
  if (tid < 128) {
    unsigned long long b0 = kred[tid][0], b1 = kred[tid][1];
    atomicMin(&keys[row0 + tid], b0 < b1 ? b0 : b1);
  }
}

// ---------- fallback f32 layer-0 (proven path, used if ws too small) ----------
__global__ __launch_bounds__(256) void l0_kernel(
    const float* __restrict__ x, const float* __restrict__ emb,
    const float* __restrict__ e0n, unsigned long long* __restrict__ keys) {
  __shared__ float As[8][128];
  __shared__ float Bs[8][128];
  __shared__ unsigned long long kred[128][16];

  int tid = threadIdx.x;
  int mb = blockIdx.x & 255;
  int nb = blockIdx.x >> 8;
  int b  = mb >> 4;
  int t0 = (mb & 15) << 7;
  const float* xb = x + ((size_t)b << 19);
  int k0 = nb << 7;

  int tx = tid & 15, ty = tid >> 4;
  int a_c = tid >> 5;
  int a_t = (tid & 31) << 2;
  int b_k = tid >> 1;
  int b_c = (tid & 1) << 2;

  float acc[8][8];
#pragma unroll
  for (int i = 0; i < 8; i++)
#pragma unroll
    for (int j = 0; j < 8; j++) acc[i][j] = 0.0f;

  const float* aptr = xb + (size_t)a_c * T_ + t0 + a_t;
  const float* bptr = emb + (size_t)(k0 + b_k) * C_ + b_c;

  for (int cc = 0; cc < C_; cc += 8) {
    float4 av = *(const float4*)(aptr + (size_t)cc * T_);
    float4 bv = *(const float4*)(bptr + cc);
    __syncthreads();
    *(float4*)&As[a_c][a_t] = av;
    Bs[b_c + 0][b_k] = bv.x;
    Bs[b_c + 1][b_k] = bv.y;
    Bs[b_c + 2][b_k] = bv.z;
    Bs[b_c + 3][b_k] = bv.w;
    __syncthreads();
#pragma unroll
    for (int c = 0; c < 8; c++) {
      float4 a0 = *(const float4*)&As[c][ty * 8];
      float4 a1 = *(const float4*)&As[c][ty * 8 + 4];
      float4 b0 = *(const float4*)&Bs[c][tx * 4];
      float4 b1 = *(const float4*)&Bs[c][64 + tx * 4];
      float av_[8] = {a0.x, a0.y, a0.z, a0.w, a1.x, a1.y, a1.z, a1.w};
      float bv_[8] = {b0.x, b0.y, b0.z, b0.w, b1.x, b1.y, b1.z, b1.w};
#pragma unroll
      for (int i = 0; i < 8; i++)
#pragma unroll
        for (int j = 0; j < 8; j++)
          acc[i][j] = fmaf(av_[i], bv_[j], acc[i][j]);
    }
  }

  int kb0 = k0 + tx * 4;
  int kb1 = k0 + 64 + tx * 4;
#pragma unroll
  for (int i = 0; i < 8; i++) {
    unsigned long long best = 0xFFFFFFFFFFFFFFFFULL;
#pragma unroll
    for (int j = 0; j < 8; j++) {
      int k = (j < 4 ? kb0 + j : kb1 + (j - 4));
      float s = e0n[k] - 2.0f * acc[i][j];
      unsigned long long key = pack_key(s, k);
      if (key < best) best = key;
    }
    kred[ty * 8 + i][tx] = best;
  }
  __syncthreads();
  if (tid < 128) {
    unsigned long long best = kred[tid][0];
#pragma unroll
    for (int j = 1; j < 16; j++) if (kred[tid][j] < best) best = kred[tid][j];
    atomicMin(&keys[(size_t)mb * 128 + tid], best);
  }
}

// ---------- gather output + loss ----------
__global__ __launch_bounds__(256) void finish_kernel(
    const float* __restrict__ x, const float* __restrict__ emb2,
    const unsigned long long* __restrict__ keys,
    const int* __restrict__ map1, const float* __restrict__ d1,
    const int* __restrict__ map2, const float* __restrict__ d2,
    float* __restrict__ out, float* __restrict__ loss_accum) {
  __shared__ int code2_l[64];
  __shared__ float rloss[64];
  __shared__ float fpart[4][64];
  int tid = threadIdx.x;
  int b  = blockIdx.x >> 5;
  int t0 = (blockIdx.x & 31) << 6;
  int tt = tid & 63, w = tid >> 6;

  if (w == 0) {
    unsigned long long key = keys[(size_t)b * T_ + t0 + tt];
    int idx0 = (int)(key & 0xFFFFFFFFULL);
    float smin = unpack_dist(key);
    int c1 = map1[idx0];
    code2_l[tt] = map2[c1];
    rloss[tt] = smin + d1[idx0] + d2[c1];
  }
  __syncthreads();

  const float* xb = x + ((size_t)b << 19);
  float* ob = out + ((size_t)b << 19);
  int code2 = code2_l[tt];
  const float* e2row = emb2 + (size_t)code2 * C_;
  float fn = 0.0f;
  for (int c4 = w * 64; c4 < w * 64 + 64; c4 += 4) {
    float4 ev = *(const float4*)(e2row + c4);
    float evv[4] = {ev.x, ev.y, ev.z, ev.w};
#pragma unroll
    for (int u = 0; u < 4; u++) {
      size_t off = (size_t)(c4 + u) * T_ + t0 + tt;
      float v = xb[off];
      fn = fmaf(v, v, fn);
      ob[off] = evv[u];
    }
  }
  fpart[w][tt] = fn;
  __syncthreads();
  if (w == 0) {
    float tot = fpart[0][tt] + fpart[1][tt] + fpart[2][tt] + fpart[3][tt] + rloss[tt];
    for (int off = 32; off > 0; off >>= 1)
      tot += __shfl_down(tot, off, 64);
    if (tt == 0) atomicAdd(loss_accum, tot);
  }
}

__global__ void finalize_kernel(const float* __restrict__ loss_accum,
                                float* __restrict__ out_loss) {
  *out_loss = 2.0f * (*loss_accum) / 8388608.0f;
}

extern "C" void kernel_launch(void* const* d_in, const int* in_sizes, int n_in,
                              void* d_out, int out_size, void* d_ws, size_t ws_size,
                              hipStream_t stream) {
  const float* x  = (const float*)d_in[0];
  const float* e0 = (const float*)d_in[1];
  const float* e1 = (const float*)d_in[2];
  const float* e2 = (const float*)d_in[3];
  float* out = (float*)d_out;
  char* ws = (char*)d_ws;

  unsigned long long* keys = (unsigned long long*)ws;        // 262144 B
  float* nrm  = (float*)(ws + 262144);                       // 12288 B
  int*   map1 = (int*)(ws + 274432);
  float* d1   = (float*)(ws + 278528);
  int*   map2 = (int*)(ws + 282624);
  float* d2   = (float*)(ws + 286720);
  float* loss_accum = (float*)(ws + 290816);
  unsigned short* embbf = (unsigned short*)(ws + 294912);    // 524288 B
  unsigned short* xT    = (unsigned short*)(ws + 819200);    // 16777216 B
  const size_t WS_FAST = 819200 + 16777216;

  hipMemsetAsync(keys, 0xFF, 262144, stream);
  hipMemsetAsync(loss_accum, 0, 4, stream);

  norms_kernel<<<12, 256, 0, stream>>>(e0, e1, e2, nrm);
  map_kernel<<<256, 256, 0, stream>>>(e0, e1, nrm, nrm + 1024, map1, d1);
  map_kernel<<<256, 256, 0, stream>>>(e1, e2, nrm + 1024, nrm + 2048, map2, d2);

  if (ws_size >= WS_FAST) {
    cvt_e0_kernel<<<256, 256, 0, stream>>>(e0, embbf);
    xpose_kernel<<<2048, 256, 0, stream>>>(x, xT);
    l0_mfma_kernel<<<2048, 256, 0, stream>>>(xT, embbf, nrm, keys);
  } else {
    l0_kernel<<<2048, 256, 0, stream>>>(x, e0, nrm, keys);
  }

  finish_kernel<<<512, 256, 0, stream>>>(x, e2, keys, map1, d1, map2, d2, out, loss_accum);
  finalize_kernel<<<1, 1, 0, stream>>>(loss_accum, out + TOTAL_ELEMS);
}

// Round 4
// 101.683 us; speedup vs baseline: 3.3104x; 1.8060x over previous
//
#include <hip/hip_runtime.h>
#include <stdint.h>

// Problem constants
#define B_  16
#define C_  256
#define T_  2048
#define K_  1024
#define TOTAL_ELEMS 8388608   // B*C*T

typedef short bf16x8 __attribute__((ext_vector_type(8)));
typedef float f32x4 __attribute__((ext_vector_type(4)));

// ---------- packed (dist, idx) ordering helpers ----------
__device__ __forceinline__ unsigned long long pack_key(float d, int idx) {
  unsigned u = __float_as_uint(d);
  u = (u & 0x80000000u) ? ~u : (u | 0x80000000u);   // monotone map f32 -> u32
  return ((unsigned long long)u << 32) | (unsigned)idx;
}
__device__ __forceinline__ float unpack_dist(unsigned long long key) {
  unsigned du = (unsigned)(key >> 32);
  unsigned bits = (du & 0x80000000u) ? (du ^ 0x80000000u) : ~du;
  return __uint_as_float(bits);
}

__device__ __forceinline__ unsigned short f2bf_rne(float f) {
  unsigned u = __float_as_uint(f);
  unsigned r = u + 0x7FFFu + ((u >> 16) & 1u);
  return (unsigned short)(r >> 16);
}

__device__ __forceinline__ void gload_lds16(const void* g, void* l) {
  __builtin_amdgcn_global_load_lds(
      (const __attribute__((address_space(1))) unsigned int*)g,
      (__attribute__((address_space(3))) unsigned int*)l, 16, 0, 0);
}

// ---------- prep: codebook row norms (blocks 0..11) + e0->bf16 (blocks 12..267) ----------
__global__ __launch_bounds__(256) void prep_kernel(
    const float* __restrict__ e0, const float* __restrict__ e1,
    const float* __restrict__ e2, float* __restrict__ nrm,
    unsigned short* __restrict__ ebf) {
  int bid = blockIdx.x;
  if (bid < 12) {
    int i = bid * 256 + threadIdx.x;     // 0..3071
    const float* e = (i < 1024) ? e0 : (i < 2048) ? e1 : e2;
    const float* p = e + (size_t)(i & 1023) * C_;
    float s = 0.0f;
    for (int c = 0; c < C_; c += 4) {
      float4 v = *(const float4*)(p + c);
      s = fmaf(v.x, v.x, s); s = fmaf(v.y, v.y, s);
      s = fmaf(v.z, v.z, s); s = fmaf(v.w, v.w, s);
    }
    nrm[i] = s;
  } else {
    int i = (bid - 12) * 256 + threadIdx.x;   // quad id, 0..65535
    float4 v = *(const float4*)(e0 + (size_t)i * 4);
    unsigned lo = (unsigned)f2bf_rne(v.x) | ((unsigned)f2bf_rne(v.y) << 16);
    unsigned hi = (unsigned)f2bf_rne(v.z) | ((unsigned)f2bf_rne(v.w) << 16);
    *(uint2*)(ebf + (size_t)i * 4) = make_uint2(lo, hi);
  }
}

// ---------- transpose+convert x[b][c][t] f32 -> xT[b*T+t][c] bf16 ----------
__global__ __launch_bounds__(256) void xpose_kernel(
    const float* __restrict__ x, unsigned short* __restrict__ xT) {
  __shared__ float ftile[64][68];
  int tid = threadIdx.x;
  int bid = blockIdx.x;
  int b  = bid >> 7;
  int t0 = ((bid >> 2) & 31) << 6;
  int c0 = (bid & 3) << 6;
  int w = tid >> 6, l = tid & 63;
  int c_loc = w * 16 + (l >> 4);
  int t_loc = (l & 15) * 4;
  const float* src = x + (size_t)b * (C_ * T_) + (size_t)(c0 + c_loc) * T_ + t0 + t_loc;
  float4 v = *(const float4*)src;
  *(float4*)&ftile[c_loc][t_loc] = v;
  __syncthreads();
  int t_row = tid >> 2;
  int cs = (tid & 3) * 16;
  unsigned pk[8];
#pragma unroll
  for (int i = 0; i < 8; i++) {
    unsigned short lo = f2bf_rne(ftile[cs + 2 * i][t_row]);
    unsigned short hi = f2bf_rne(ftile[cs + 2 * i + 1][t_row]);
    pk[i] = (unsigned)lo | ((unsigned)hi << 16);
  }
  unsigned short* dst = xT + ((size_t)(b * T_ + t0 + t_row) * C_ + c0 + cs);
  *(uint4*)dst       = make_uint4(pk[0], pk[1], pk[2], pk[3]);
  *((uint4*)dst + 1) = make_uint4(pk[4], pk[5], pk[6], pk[7]);
}

// ---------- code-to-code maps as tiled f32 GEMM + argmin ----------
// 512 blocks: map m = bid>>8; 16x16 tiles of 64x64; K=256 staged in LDS.
// keysM[m*1024 + a_row] = min over B rows of pack(nB[j] - 2*dot, j)
__global__ __launch_bounds__(256) void map_tile_kernel(
    const float* __restrict__ e0, const float* __restrict__ e1,
    const float* __restrict__ e2, const float* __restrict__ nrm,
    unsigned long long* __restrict__ keysM) {
  __shared__ float As[16][68];   // [k][row], pad 68 -> 2-way max
  __shared__ float Bs[16][68];
  int bid = blockIdx.x;
  int m = bid >> 8;
  int tb = bid & 255;
  int ar0 = (tb >> 4) << 6;
  int br0 = (tb & 15) << 6;
  const float* Ap = m ? e1 : e0;
  const float* Bp = m ? e2 : e1;
  const float* nB = nrm + (m + 1) * 1024;

  int tid = threadIdx.x;
  int ty = tid >> 4, tx = tid & 15;
  int srow = tid >> 2;           // 0..63
  int skp  = (tid & 3) << 2;     // 0,4,8,12

  float acc[4][4];
#pragma unroll
  for (int i = 0; i < 4; i++)
#pragma unroll
    for (int j = 0; j < 4; j++) acc[i][j] = 0.0f;

  const float* gA = Ap + (size_t)(ar0 + srow) * C_ + skp;
  const float* gB = Bp + (size_t)(br0 + srow) * C_ + skp;

  for (int kk = 0; kk < C_; kk += 16) {
    float4 av = *(const float4*)(gA + kk);
    float4 bv = *(const float4*)(gB + kk);
    __syncthreads();
    As[skp + 0][srow] = av.x; As[skp + 1][srow] = av.y;
    As[skp + 2][srow] = av.z; As[skp + 3][srow] = av.w;
    Bs[skp + 0][srow] = bv.x; Bs[skp + 1][srow] = bv.y;
    Bs[skp + 2][srow] = bv.z; Bs[skp + 3][srow] = bv.w;
    __syncthreads();
#pragma unroll
    for (int k = 0; k < 16; k++) {
      float4 a4 = *(const float4*)&As[k][ty * 4];
      float4 b4 = *(const float4*)&Bs[k][tx * 4];
      float aa[4] = {a4.x, a4.y, a4.z, a4.w};
      float bb[4] = {b4.x, b4.y, b4.z, b4.w};
#pragma unroll
      for (int i = 0; i < 4; i++)
#pragma unroll
        for (int j = 0; j < 4; j++)
          acc[i][j] = fmaf(aa[i], bb[j], acc[i][j]);
    }
  }

  float nv[4];
#pragma unroll
  for (int j = 0; j < 4; j++) nv[j] = nB[br0 + tx * 4 + j];

#pragma unroll
  for (int i = 0; i < 4; i++) {
    unsigned long long best = 0xFFFFFFFFFFFFFFFFULL;
#pragma unroll
    for (int j = 0; j < 4; j++) {
      int code = br0 + tx * 4 + j;
      float s = nv[j] - 2.0f * acc[i][j];
      unsigned long long key = pack_key(s, code);
      if (key < best) best = key;
    }
#pragma unroll
    for (int off = 1; off < 16; off <<= 1) {
      unsigned long long o = __shfl_xor(best, off, 64);
      if (o < best) best = o;
    }
    if (tx == 0)
      atomicMin(&keysM[m * 1024 + ar0 + ty * 4 + i], best);
  }
}

// ---------- layer-0 MFMA distance GEMM + argmin ----------
// 128x128 tile, BK=32, 4 waves (2x2), per-wave 64x64 via 4x4 16x16x32 frags.
__global__ __launch_bounds__(256) void l0_mfma_kernel(
    const unsigned short* __restrict__ xT, const unsigned short* __restrict__ ebf,
    const float* __restrict__ e0n, unsigned long long* __restrict__ keys) {
  __shared__ __align__(16) unsigned short AB[2][2][128][32];
  __shared__ unsigned long long kred[128][2];

  int tid = threadIdx.x;
  int l = tid & 63, w = tid >> 6;
  int wr = w >> 1, wc = w & 1;
  int mb = blockIdx.x & 255, nb = blockIdx.x >> 8;
  int row0 = mb << 7, kb = nb << 7;

  int sm = w * 32 + (l >> 2);
  int ks = (l & 3) ^ ((l >> 2) & 3);
  const unsigned short* gA = xT + ((size_t)(row0 + sm) * C_ + ks * 8);
  const unsigned short* gB = ebf + ((size_t)(kb + sm) * C_ + ks * 8);

  f32x4 acc[4][4];
#pragma unroll
  for (int mi = 0; mi < 4; mi++)
#pragma unroll
    for (int ni = 0; ni < 4; ni++) acc[mi][ni] = (f32x4){0.f, 0.f, 0.f, 0.f};

#define STAGE(buf, kk) do {                                              \
    char* baseA = (char*)&AB[(buf)][0][0][0] + w * 2048;                 \
    char* baseB = (char*)&AB[(buf)][1][0][0] + w * 2048;                 \
    gload_lds16(gA + (size_t)(kk) * 32, baseA);                          \
    gload_lds16(gA + (size_t)16 * C_ + (size_t)(kk) * 32, baseA + 1024); \
    gload_lds16(gB + (size_t)(kk) * 32, baseB);                          \
    gload_lds16(gB + (size_t)16 * C_ + (size_t)(kk) * 32, baseB + 1024); \
  } while (0)

  STAGE(0, 0);
  __syncthreads();

  int lr = l & 15, lg = l >> 4;
  int slot = lg ^ (lr & 3);
  int buf = 0;
  for (int kk = 0; kk < 8; kk++) {
    if (kk < 7) STAGE(buf ^ 1, kk + 1);
    bf16x8 aF[4], bF[4];
#pragma unroll
    for (int mi = 0; mi < 4; mi++)
      aF[mi] = *(const bf16x8*)&AB[buf][0][wr * 64 + mi * 16 + lr][slot * 8];
#pragma unroll
    for (int ni = 0; ni < 4; ni++)
      bF[ni] = *(const bf16x8*)&AB[buf][1][wc * 64 + ni * 16 + lr][slot * 8];
#pragma unroll
    for (int mi = 0; mi < 4; mi++)
#pragma unroll
      for (int ni = 0; ni < 4; ni++)
        acc[mi][ni] = __builtin_amdgcn_mfma_f32_16x16x32_bf16(
            aF[mi], bF[ni], acc[mi][ni], 0, 0, 0);
    __syncthreads();
    buf ^= 1;
  }
#undef STAGE

  float nv[4];
#pragma unroll
  for (int ni = 0; ni < 4; ni++) nv[ni] = e0n[kb + wc * 64 + ni * 16 + lr];

#pragma unroll
  for (int mi = 0; mi < 4; mi++) {
#pragma unroll
    for (int r = 0; r < 4; r++) {
      unsigned long long best = 0xFFFFFFFFFFFFFFFFULL;
#pragma unroll
      for (int ni = 0; ni < 4; ni++) {
        int code = kb + wc * 64 + ni * 16 + lr;
        float s = nv[ni] - 2.0f * acc[mi][ni][r];
        unsigned long long key = pack_key(s, code);
        if (key < best) best = key;
      }
#pragma unroll
      for (int off = 1; off < 16; off <<= 1) {
        unsigned long long o = __shfl_xor(best, off, 64);
        if (o < best) best = o;
      }
      if (lr == 0) kred[wr * 64 + mi * 16 + lg * 4 + r][wc] = best;
    }
  }
  __syncthreads();
  if (tid < 128) {
    unsigned long long b0 = kred[tid][0], b1 = kred[tid][1];
    atomicMin(&keys[row0 + tid], b0 < b1 ? b0 : b1);
  }
}

// ---------- gather output + loss (reads key tables directly) ----------
__global__ __launch_bounds__(256) void finish_kernel(
    const float* __restrict__ x, const float* __restrict__ emb2,
    const unsigned long long* __restrict__ keys,
    const unsigned long long* __restrict__ keysM,
    const float* __restrict__ nrm,
    float* __restrict__ out, float* __restrict__ loss_accum) {
  __shared__ int code2_l[64];
  __shared__ float rloss[64];
  __shared__ float fpart[4][64];
  int tid = threadIdx.x;
  int b  = blockIdx.x >> 5;
  int t0 = (blockIdx.x & 31) << 6;
  int tt = tid & 63, w = tid >> 6;

  if (w == 0) {
    unsigned long long key0 = keys[(size_t)b * T_ + t0 + tt];
    int idx0 = (int)(key0 & 0xFFFFFFFFULL);
    float s0 = unpack_dist(key0);
    unsigned long long k1 = keysM[idx0];
    int c1 = (int)(k1 & 0xFFFFFFFFULL);
    unsigned long long k2 = keysM[1024 + c1];
    code2_l[tt] = (int)(k2 & 0xFFFFFFFFULL);
    rloss[tt] = s0 + nrm[idx0] + unpack_dist(k1) + nrm[1024 + c1] + unpack_dist(k2);
  }
  __syncthreads();

  const float* xb = x + ((size_t)b << 19);
  float* ob = out + ((size_t)b << 19);
  int code2 = code2_l[tt];
  const float* e2row = emb2 + (size_t)code2 * C_;
  float fn = 0.0f;
  for (int c4 = w * 64; c4 < w * 64 + 64; c4 += 4) {
    float4 ev = *(const float4*)(e2row + c4);
    float evv[4] = {ev.x, ev.y, ev.z, ev.w};
#pragma unroll
    for (int u = 0; u < 4; u++) {
      size_t off = (size_t)(c4 + u) * T_ + t0 + tt;
      float v = xb[off];
      fn = fmaf(v, v, fn);
      ob[off] = evv[u];
    }
  }
  fpart[w][tt] = fn;
  __syncthreads();
  if (w == 0) {
    float tot = fpart[0][tt] + fpart[1][tt] + fpart[2][tt] + fpart[3][tt] + rloss[tt];
    for (int off = 32; off > 0; off >>= 1)
      tot += __shfl_down(tot, off, 64);
    if (tt == 0) atomicAdd(loss_accum, tot);
  }
}

__global__ void finalize_kernel(const float* __restrict__ loss_accum,
                                float* __restrict__ out_loss) {
  *out_loss = 2.0f * (*loss_accum) / 8388608.0f;
}

extern "C" void kernel_launch(void* const* d_in, const int* in_sizes, int n_in,
                              void* d_out, int out_size, void* d_ws, size_t ws_size,
                              hipStream_t stream) {
  const float* x  = (const float*)d_in[0];
  const float* e0 = (const float*)d_in[1];
  const float* e1 = (const float*)d_in[2];
  const float* e2 = (const float*)d_in[3];
  float* out = (float*)d_out;
  char* ws = (char*)d_ws;

  unsigned long long* keys  = (unsigned long long*)ws;            // 262144 B
  unsigned long long* keysM = (unsigned long long*)(ws + 262144); // 16384 B
  float* nrm  = (float*)(ws + 278528);                            // 12288 B
  float* loss_accum = (float*)(ws + 290816);                      // 4 B
  unsigned short* embbf = (unsigned short*)(ws + 294912);         // 524288 B
  unsigned short* xT    = (unsigned short*)(ws + 819200);         // 16777216 B

  hipMemsetAsync(keys, 0xFF, 262144 + 16384, stream);   // keys + keysM contiguous
  hipMemsetAsync(loss_accum, 0, 4, stream);

  prep_kernel<<<268, 256, 0, stream>>>(e0, e1, e2, nrm, embbf);
  xpose_kernel<<<2048, 256, 0, stream>>>(x, xT);
  l0_mfma_kernel<<<2048, 256, 0, stream>>>(xT, embbf, nrm, keys);
  map_tile_kernel<<<512, 256, 0, stream>>>(e0, e1, e2, nrm, keysM);
  finish_kernel<<<512, 256, 0, stream>>>(x, e2, keys, keysM, nrm, out, loss_accum);
  finalize_kernel<<<1, 1, 0, stream>>>(loss_accum, out + TOTAL_ELEMS);
}